// Round 17
// baseline (846.348 us; speedup 1.0000x reference)
//
#include <hip/hip_runtime.h>
#include <hip/hip_cooperative_groups.h>
namespace cg = cooperative_groups;

#define N_NODES 100000
#define N_EDGES 1000000
#define DIM 64
#define N_GRAPHS 1024
#define OUT_DIM 16
#define NLAYERS 4

#define BN 64        // nodes per virtual layer-block
#define NB 1563      // ceil(N_NODES/BN) virtual blocks
#define COOP_GRID 1024
#define NUM_CU 256
#define RPW 16       // rows per wave = 2 padded 8-row groups
#define SA 65        // LDS row stride: 65%32==1 -> 2-way alias, free
#define NGRP 12500   // N_NODES/8 wave-groups

// ---- bucket sort params ----
#define NBKT2 391            // ceil(N_NODES/256) buckets of 256 dst nodes
#define BCH 2048             // edges per p1 block
#define NBLK1 489            // ceil(N_EDGES/BCH)
#define SLACK 1800           // per-bucket region slack: 256*7 pad + 8
#define EPB (N_EDGES + NBKT2 * SLACK)
#define SENTSRC N_NODES      // sentinel src -> zero bf16 row

typedef unsigned short ushort8_t __attribute__((ext_vector_type(8)));

__device__ __forceinline__ float b2f(unsigned short u) {
    union { unsigned int i; float f; } c;
    c.i = ((unsigned int)u) << 16;
    return c.f;
}
__device__ __forceinline__ unsigned short f2b(float f) {  // RNE
    union { float f; unsigned int i; } c;
    c.f = f;
    return (unsigned short)((c.i + 0x7FFFu + ((c.i >> 16) & 1u)) >> 16);
}

__device__ __forceinline__ int blk_excl_scan_256(int v, int tid, int* tmp) {
    int lane = tid & 63, w = tid >> 6;
    int inc = v;
#pragma unroll
    for (int o = 1; o < 64; o <<= 1) { int u = __shfl_up(inc, o, 64); if (lane >= o) inc += u; }
    __syncthreads();
    if (lane == 63) tmp[w] = inc;
    __syncthreads();
    if (tid == 0) { int r = 0; for (int i = 0; i < 4; ++i) { int t2 = tmp[i]; tmp[i] = r; r += t2; } }
    __syncthreads();
    return inc - v + tmp[w];
}

__device__ __forceinline__ void flush_row(float* a, int row, int lane, float* agg_s) {
#pragma unroll
    for (int j = 0; j < 8; ++j) {
        a[j] += __shfl_xor(a[j], 8, 64);
        a[j] += __shfl_xor(a[j], 16, 64);
        a[j] += __shfl_xor(a[j], 32, 64);
    }
    if ((lane >> 3) == 0) {
#pragma unroll
        for (int j = 0; j < 8; ++j)
            agg_s[row * SA + (lane & 7) * 8 + j] = a[j];
    }
}

// ================= phase bodies (shared by coop mega + split kernels) ========

__device__ void hist_body(int pb, int tid, const int* __restrict__ dst,
                          int* __restrict__ hblk, int* h) {
    __syncthreads();   // protect h reuse across grid-stride iterations
    for (int i = tid; i < NBKT2; i += 256) h[i] = 0;
    __syncthreads();
    int e0 = pb * BCH;
    int nloc = min(BCH, N_EDGES - e0);
    for (int i = tid; i < nloc; i += 256) atomicAdd(&h[dst[e0 + i] >> 8], 1);  // LDS int: native
    __syncthreads();
    for (int i = tid; i < NBKT2; i += 256) hblk[(size_t)pb * NBKT2 + i] = h[i];
}

__device__ void colscan_body(int c, int tid, int* __restrict__ hblk,
                             int* __restrict__ gsize, int* tmp) {
    int i0 = 2 * tid, i1 = 2 * tid + 1;
    int a = (i0 < NBLK1) ? hblk[(size_t)i0 * NBKT2 + c] : 0;
    int b = (i1 < NBLK1) ? hblk[(size_t)i1 * NBKT2 + c] : 0;
    int s = blk_excl_scan_256(a + b, tid, tmp);
    if (i0 < NBLK1) hblk[(size_t)i0 * NBKT2 + c] = s;
    if (i1 < NBLK1) hblk[(size_t)i1 * NBKT2 + c] = s + a;
    if (tid == 255) gsize[c] = s + a + b;   // column total
}

__device__ void scanb2_body(int tid, const int* __restrict__ gsize,
                            int* __restrict__ Abase, int* __restrict__ Bbase, int* tmp) {
    int c0 = 2 * tid, c1 = 2 * tid + 1;
    int a = (c0 < NBKT2) ? gsize[c0] : 0;
    int b = (c1 < NBKT2) ? gsize[c1] : 0;
    int s = blk_excl_scan_256(a + b, tid, tmp);
    if (c0 < NBKT2) Abase[c0] = s;
    if (c1 < NBKT2) Abase[c1] = s + a;
    int a2 = (c0 < NBKT2) ? a + SLACK : 0;
    int b2 = (c1 < NBKT2) ? b + SLACK : 0;
    int s2 = blk_excl_scan_256(a2 + b2, tid, tmp);
    if (c0 < NBKT2) Bbase[c0] = s2;
    if (c1 < NBKT2) Bbase[c1] = s2 + a2;
}

// smem layout: h[391] start[391] curb[391] resv[391] tmp[4] sortedv[2048] sortedb[2048 u16]
__device__ void p1_body(int pb, int tid, const int* __restrict__ src,
                        const int* __restrict__ dst, const int* __restrict__ Abase,
                        const int* __restrict__ hblk, int* __restrict__ edgesA, int* smem) {
    int* h = smem;
    int* start = h + NBKT2;
    int* curb = start + NBKT2;
    int* resv = curb + NBKT2;
    int* tmp = resv + NBKT2;
    int* sortedv = tmp + 4;
    unsigned short* sortedb = (unsigned short*)(sortedv + BCH);
    __syncthreads();   // protect smem reuse
    int e0 = pb * BCH;
    int nloc = min(BCH, N_EDGES - e0);
    for (int i = tid; i < NBKT2; i += 256) h[i] = 0;
    __syncthreads();
    int myc[8], myv[8];
#pragma unroll
    for (int k = 0; k < 8; ++k) {
        int i = k * 256 + tid;
        if (i < nloc) {
            int e = e0 + i;
            int d = dst[e];
            myc[k] = d >> 8;
            myv[k] = ((d & 255) << 17) | src[e];   // 8b local dst | 17b src
            atomicAdd(&h[myc[k]], 1);
        } else myc[k] = -1;
    }
    __syncthreads();
    {
        int a = (2 * tid < NBKT2) ? h[2 * tid] : 0;
        int b = (2 * tid + 1 < NBKT2) ? h[2 * tid + 1] : 0;
        int s = blk_excl_scan_256(a + b, tid, tmp);
        if (2 * tid < NBKT2) start[2 * tid] = s;
        if (2 * tid + 1 < NBKT2) start[2 * tid + 1] = s + a;
    }
    __syncthreads();
    for (int i = tid; i < NBKT2; i += 256) curb[i] = start[i];
    __syncthreads();
#pragma unroll
    for (int k = 0; k < 8; ++k) if (myc[k] >= 0) {
        int r = atomicAdd(&curb[myc[k]], 1);
        sortedv[r] = myv[k];
        sortedb[r] = (unsigned short)myc[k];
    }
    __syncthreads();
    for (int i = tid; i < NBKT2; i += 256) resv[i] = hblk[(size_t)pb * NBKT2 + i];
    __syncthreads();
    for (int i = tid; i < nloc; i += 256) {
        int c = sortedb[i];
        edgesA[Abase[c] + resv[c] + (i - start[c])] = sortedv[i];
    }
}

// smem: cnt[256] off[256] pend[256] curx[256] tmp[4]
__device__ void p2_body(int b, int tid, const int* __restrict__ gsize,
                        const int* __restrict__ Abase, const int* __restrict__ Bbase,
                        const int* __restrict__ edgesA, int* __restrict__ edgesB,
                        int* __restrict__ rpS, int* __restrict__ wend8, int* smem) {
    int* cnt = smem;
    int* off = cnt + 256;
    int* pend = off + 256;
    int* curx = pend + 256;
    int* tmp = curx + 256;
    __syncthreads();   // protect smem reuse
    int nb0 = b * 256;
    int nn = min(256, N_NODES - nb0);
    int ne = gsize[b];
    int abase = Abase[b], bbase = Bbase[b];
    cnt[tid] = 0;
    __syncthreads();
    for (int i = tid; i < ne; i += 256) atomicAdd(&cnt[edgesA[abase + i] >> 17], 1);
    __syncthreads();
    int c = cnt[tid];
    int c8 = (tid < nn) ? ((c + 7) & ~7) : 0;
    int o = blk_excl_scan_256(c8, tid, tmp);
    off[tid] = o; pend[tid] = o + c8; curx[tid] = bbase + o;
    __syncthreads();
    int gc = nn >> 3;
    if (tid < gc) {
        rpS[(nb0 >> 3) + tid] = bbase + off[tid * 8];
        wend8[(nb0 >> 3) + tid] = bbase + pend[tid * 8 + 7];
    }
    for (int i = tid; i < ne; i += 256) {
        int p = edgesA[abase + i];
        int dl = p >> 17;
        int pos = atomicAdd(&curx[dl], 1);
        edgesB[pos] = ((dl & 7) << 17) | (p & 0x1FFFF);
    }
    __syncthreads();
    if (tid < nn) {
        int pe = bbase + pend[tid];
        int sent = ((tid & 7) << 17) | SENTSRC;
        for (int pos = curx[tid]; pos < pe; ++pos) edgesB[pos] = sent;
    }
}

__device__ void layer_body(int vb, int tid,
                           const ushort8_t* __restrict__ hbf_in, ushort8_t* __restrict__ hbf_out,
                           const float* __restrict__ Wrel, const float* __restrict__ brel,
                           const float* __restrict__ Wroot,
                           const int* __restrict__ rpS, const int* __restrict__ wend8,
                           const int* __restrict__ edges8,
                           const int* __restrict__ batch, float* __restrict__ g,
                           bool last, float* agg_s) {
    const int lane = tid & 63;
    const int wave = __builtin_amdgcn_readfirstlane(tid >> 6);
    const int grp8 = lane >> 3;
    const int gl8 = lane & 7;
    const int node0 = vb * BN;
    const int nvalid = min(BN, N_NODES - node0);

    __syncthreads();   // protect agg_s reuse across steal iterations
#pragma unroll
    for (int r = 0; r < RPW; ++r) agg_s[(wave * RPW + r) * SA + lane] = 0.f;

    // Phase A: two 8-row segments per wave, flat padded edge stream, 2-chunk pipeline
#pragma unroll
    for (int seg = 0; seg < 2; ++seg) {
        const int gg = vb * 8 + wave * 2 + seg;
        if (gg >= NGRP) break;
        const int eb = rpS[gg];
        const int nst = (wend8[gg] - eb) >> 3;
        if (nst <= 0) continue;
        const int rbase = wave * RPW + seg * 8;

        float a[8];
#pragma unroll
        for (int j = 0; j < 8; ++j) a[j] = 0.f;
        int cur = -1;

        const int lmax = nst * 8 - 1;
        const int l32 = lane & 31;
        int pv0 = edges8[eb + min(l32, lmax)];
        int pv1 = edges8[eb + min(32 + l32, lmax)];
        ushort8_t U0[4];
#pragma unroll
        for (int i = 0; i < 4; ++i) {
            int ps = __shfl(pv0, i * 8 + grp8, 64);
            U0[i] = hbf_in[(size_t)(ps & 0x1FFFF) * 8 + gl8];
        }
        for (int c = 0; c * 4 < nst; ++c) {
            int pvn = edges8[eb + min((c + 2) * 32 + l32, lmax)];
            ushort8_t Un[4];
#pragma unroll
            for (int i = 0; i < 4; ++i) {
                int ps = __shfl(pv1, i * 8 + grp8, 64);
                Un[i] = hbf_in[(size_t)(ps & 0x1FFFF) * 8 + gl8];
            }
#pragma unroll
            for (int i = 0; i < 4; ++i) {
                int t = c * 4 + i;
                if (t < nst) {
                    int lr = __builtin_amdgcn_readfirstlane(__shfl(pv0, i * 8, 64)) >> 17;
                    if (lr != cur) {
                        if (cur >= 0) flush_row(a, rbase + cur, lane, agg_s);
                        cur = lr;
#pragma unroll
                        for (int j = 0; j < 8; ++j) a[j] = 0.f;
                    }
#pragma unroll
                    for (int j = 0; j < 8; ++j) a[j] += b2f(U0[i][j]);
                }
            }
            pv0 = pv1; pv1 = pvn;
#pragma unroll
            for (int i = 0; i < 4; ++i) U0[i] = Un[i];
        }
        if (cur >= 0) flush_row(a, rbase + cur, lane, agg_s);
    }
    __syncthreads();

    // Phase B: node = lane, dims [wave*16, +16); own row read from bf16
    const int d0 = wave * 16;
    float out[16];
#pragma unroll
    for (int j = 0; j < 16; ++j) out[j] = brel[d0 + j];
    const float* ar = &agg_s[lane * SA];
    const int nrow = min(node0 + lane, N_NODES - 1);
    const ushort8_t* xrow8 = &hbf_in[(size_t)nrow * 8];
    for (int kk = 0; kk < 8; ++kk) {
        ushort8_t xq = xrow8[kk];
#pragma unroll
        for (int c = 0; c < 8; ++c) {
            int k = kk * 8 + c;
            float av = ar[k];
            float xv = b2f(xq[c]);
            const float* wr = &Wrel[k * DIM + d0];
            const float* wo = &Wroot[k * DIM + d0];
#pragma unroll
            for (int j = 0; j < 16; ++j)
                out[j] = fmaf(av, wr[j], fmaf(xv, wo[j], out[j]));
        }
    }

    __syncthreads();
#pragma unroll
    for (int j = 0; j < 16; ++j) agg_s[lane * SA + d0 + j] = fmaxf(out[j], 0.f);
    __syncthreads();

    if (last) {
        if (wave == 0) {   // fused global_add_pool (batch sorted)
            float acc = 0.f;
            int cur = batch[node0];
            for (int nl = 0; nl < nvalid; ++nl) {
                int bv = batch[node0 + nl];
                float v = agg_s[nl * SA + lane];
                if (bv != cur) {
                    unsafeAtomicAdd(&g[(size_t)cur * DIM + lane], acc);
                    acc = 0.f; cur = bv;
                }
                acc += v;
            }
            unsafeAtomicAdd(&g[(size_t)cur * DIM + lane], acc);
        }
    } else {
        for (int i = tid; i < nvalid * 8; i += 256) {
            int nl = i >> 3, c8 = i & 7;
            const float* xp = &agg_s[nl * SA + c8 * 8];
            ushort8_t b;
#pragma unroll
            for (int j = 0; j < 8; ++j) b[j] = f2b(xp[j]);
            hbf_out[(size_t)(node0 + nl) * 8 + c8] = b;
        }
    }
}

__device__ void head_body(int gid, const float* __restrict__ g,
                          const float* __restrict__ W1, const float* __restrict__ b1,
                          const float* __restrict__ W2, const float* __restrict__ b2,
                          float* __restrict__ y) {
    float t[DIM];
#pragma unroll
    for (int d = 0; d < DIM; ++d) t[d] = b1[d];
    const float4* gp = reinterpret_cast<const float4*>(g + (size_t)gid * DIM);
    for (int kk = 0; kk < DIM / 4; ++kk) {
        float4 gv = gp[kk];
        float ga[4] = {gv.x, gv.y, gv.z, gv.w};
#pragma unroll
        for (int c = 0; c < 4; ++c) {
            int k = 4 * kk + c;
            float v = ga[c];
#pragma unroll
            for (int d = 0; d < DIM; ++d) t[d] = fmaf(v, W1[k * DIM + d], t[d]);
        }
    }
#pragma unroll
    for (int d = 0; d < DIM; ++d) t[d] = fmaxf(t[d], 0.f);
    for (int o = 0; o < OUT_DIM; ++o) {
        float acc = b2[o];
#pragma unroll
        for (int d = 0; d < DIM; ++d) acc = fmaf(t[d], W2[d * OUT_DIM + o], acc);
        y[(size_t)gid * OUT_DIM + o] = acc;
    }
}

// ================= params =====================================================
struct MegaParams {
    const int* src; const int* dst; const int* batch;
    const float4* x;
    const float* Wrel; const float* brel; const float* Wroot;
    const float* W1; const float* b1; const float* W2; const float* b2;
    float* y;
    ushort4* bf0; ushort4* bf1;
    int* rpS; int* wend8; int* gsize; int* Abase; int* Bbase;
    int* hblk; int* edgesA; int* edgesB; float* g; int* steal;
};

// ================= cooperative mega-kernel (grid-stride phases) ===============
__global__ __launch_bounds__(256, 4) void mega_kernel(MegaParams P) {
    __shared__ int smem[4640];   // union: p1 needs 4640 ints >= layer's 4160 floats
    __shared__ int vb_s;
    cg::grid_group grid = cg::this_grid();
    const int bid = blockIdx.x, tid = threadIdx.x;
    const int nblk = gridDim.x;

    // phase 0: prep (hist + tobf + zero g + sentinels + steal init)
    for (int pb = bid; pb < NBLK1; pb += nblk)
        hist_body(pb, tid, P.dst, P.hblk, smem);
    const int n4 = N_NODES * 16;
    for (int i = bid * 256 + tid; i < n4; i += nblk * 256) {
        float4 v = P.x[i];
        ushort4 b; b.x = f2b(v.x); b.y = f2b(v.y); b.z = f2b(v.z); b.w = f2b(v.w);
        P.bf0[i] = b;
    }
    const int g4 = N_GRAPHS * 16;
    float4 z4 = make_float4(0.f, 0.f, 0.f, 0.f);
    for (int i = bid * 256 + tid; i < g4; i += nblk * 256)
        reinterpret_cast<float4*>(P.g)[i] = z4;
    if (bid == 0) {
        if (tid < 32) {
            ushort4 z; z.x = 0; z.y = 0; z.z = 0; z.w = 0;
            if (tid < 16) P.bf0[(size_t)N_NODES * 16 + tid] = z;
            else          P.bf1[(size_t)N_NODES * 16 + (tid - 16)] = z;
        }
        if (tid >= 32 && tid < 40) P.steal[tid - 32] = 0;
    }
    grid.sync();

    // phase 1: column scan
    for (int c = bid; c < NBKT2; c += nblk)
        colscan_body(c, tid, P.hblk, P.gsize, smem);
    grid.sync();

    // phase 2: bucket-total scan (block 0)
    if (bid == 0) scanb2_body(tid, P.gsize, P.Abase, P.Bbase, smem);
    grid.sync();

    // phase 3: p1 bucket sort
    for (int pb = bid; pb < NBLK1; pb += nblk)
        p1_body(pb, tid, P.src, P.dst, P.Abase, P.hblk, P.edgesA, smem);
    grid.sync();

    // phase 4: p2 per-bucket node sort + padding
    for (int b = bid; b < NBKT2; b += nblk)
        p2_body(b, tid, P.gsize, P.Abase, P.Bbase, P.edgesA, P.edgesB, P.rpS, P.wend8, smem);
    grid.sync();

    // 4 GraphConv layers (work-stealing over 1563 vblocks)
    for (int l = 0; l < NLAYERS; ++l) {
        const ushort8_t* bin = (const ushort8_t*)((l & 1) ? P.bf1 : P.bf0);
        ushort8_t* bout = (ushort8_t*)((l & 1) ? P.bf0 : P.bf1);
        const float* Wr = P.Wrel + (size_t)l * DIM * DIM;
        const float* br = P.brel + (size_t)l * DIM;
        const float* Wo = P.Wroot + (size_t)l * DIM * DIM;
        const bool last = (l == NLAYERS - 1);
        for (;;) {
            __syncthreads();
            if (tid == 0) vb_s = atomicAdd(&P.steal[l], 1);
            __syncthreads();
            int vb = vb_s;
            if (vb >= NB) break;
            layer_body(vb, tid, bin, bout, Wr, br, Wo,
                       P.rpS, P.wend8, P.edgesB, P.batch, P.g, last, (float*)smem);
        }
        grid.sync();
    }

    // head
    for (int gid = bid * 256 + tid; gid < N_GRAPHS; gid += nblk * 256)
        head_body(gid, P.g, P.W1, P.b1, P.W2, P.b2, P.y);
}

// ================= split-path kernels (R15 fallback, known-good) ==============
__global__ __launch_bounds__(256) void prep_kernel(const int* __restrict__ dst,
                                                   int* __restrict__ hblk,
                                                   const float4* __restrict__ x,
                                                   ushort4* __restrict__ bf0,
                                                   ushort4* __restrict__ bf1,
                                                   float* __restrict__ g) {
    __shared__ int h[NBKT2];
    int tid = threadIdx.x, bid = blockIdx.x;
    hist_body(bid, tid, dst, hblk, h);
    const int n4 = N_NODES * 16;
    for (int i = bid * 256 + tid; i < n4; i += NBLK1 * 256) {
        float4 v = x[i];
        ushort4 b; b.x = f2b(v.x); b.y = f2b(v.y); b.z = f2b(v.z); b.w = f2b(v.w);
        bf0[i] = b;
    }
    const int g4 = N_GRAPHS * 16;
    float4 z4 = make_float4(0.f, 0.f, 0.f, 0.f);
    for (int i = bid * 256 + tid; i < g4; i += NBLK1 * 256)
        reinterpret_cast<float4*>(g)[i] = z4;
    if (bid == 0 && tid < 32) {
        ushort4 z; z.x = 0; z.y = 0; z.z = 0; z.w = 0;
        if (tid < 16) bf0[(size_t)N_NODES * 16 + tid] = z;
        else          bf1[(size_t)N_NODES * 16 + (tid - 16)] = z;
    }
}

__global__ __launch_bounds__(256) void colscan_kernel(int* __restrict__ hblk,
                                                      int* __restrict__ gsize) {
    __shared__ int tmp[4];
    colscan_body(blockIdx.x, threadIdx.x, hblk, gsize, tmp);
}

__global__ __launch_bounds__(256) void scanb2_kernel(const int* __restrict__ gsize,
                                                     int* __restrict__ Abase,
                                                     int* __restrict__ Bbase) {
    __shared__ int tmp[4];
    scanb2_body(threadIdx.x, gsize, Abase, Bbase, tmp);
}

__global__ __launch_bounds__(256) void p1_kernel(const int* __restrict__ src,
                                                 const int* __restrict__ dst,
                                                 const int* __restrict__ Abase,
                                                 const int* __restrict__ hblk,
                                                 int* __restrict__ edgesA) {
    __shared__ int smem[4640];
    p1_body(blockIdx.x, threadIdx.x, src, dst, Abase, hblk, edgesA, smem);
}

__global__ __launch_bounds__(256) void p2_kernel(const int* __restrict__ gsize,
                                                 const int* __restrict__ Abase,
                                                 const int* __restrict__ Bbase,
                                                 const int* __restrict__ edgesA,
                                                 int* __restrict__ edgesB,
                                                 int* __restrict__ rpS,
                                                 int* __restrict__ wend8) {
    __shared__ int smem[1028];
    p2_body(blockIdx.x, threadIdx.x, gsize, Abase, Bbase, edgesA, edgesB, rpS, wend8, smem);
}

template <bool LAST>
__global__ __launch_bounds__(256) void layer_kernel(
    const ushort8_t* __restrict__ hbf_in, ushort8_t* __restrict__ hbf_out,
    const float* __restrict__ Wrel, const float* __restrict__ brel,
    const float* __restrict__ Wroot,
    const int* __restrict__ rpS, const int* __restrict__ wend8,
    const int* __restrict__ edges8,
    const int* __restrict__ batch, float* __restrict__ g) {
    __shared__ float agg_s[BN * SA];
    layer_body(blockIdx.x, threadIdx.x, hbf_in, hbf_out, Wrel, brel, Wroot,
               rpS, wend8, edges8, batch, g, LAST, agg_s);
}

__global__ __launch_bounds__(256) void head_kernel(
    const float* __restrict__ g, const float* __restrict__ W1, const float* __restrict__ b1,
    const float* __restrict__ W2, const float* __restrict__ b2, float* __restrict__ y) {
    int gid = blockIdx.x * blockDim.x + threadIdx.x;
    if (gid < N_GRAPHS) head_body(gid, g, W1, b1, W2, b2, y);
}

// ================= host =======================================================
extern "C" void kernel_launch(void* const* d_in, const int* in_sizes, int n_in,
                              void* d_out, int out_size, void* d_ws, size_t ws_size,
                              hipStream_t stream) {
    const float* x     = (const float*)d_in[0];
    const int*   eidx  = (const int*)d_in[1];
    const int*   batch = (const int*)d_in[2];
    const float* Wrel  = (const float*)d_in[3];
    const float* brel  = (const float*)d_in[4];
    const float* Wroot = (const float*)d_in[5];
    const float* W1    = (const float*)d_in[6];
    const float* b1    = (const float*)d_in[7];
    const float* W2    = (const float*)d_in[8];
    const float* b2    = (const float*)d_in[9];
    float* y = (float*)d_out;

    char* ws = (char*)d_ws;
    const size_t BFBYTES = (size_t)(N_NODES + 1) * DIM * sizeof(unsigned short);
    size_t off = 0;
    ushort4* bf0 = (ushort4*)(ws + off); off += (BFBYTES + 255) / 256 * 256;
    ushort4* bf1 = (ushort4*)(ws + off); off += (BFBYTES + 255) / 256 * 256;
    int* rpS    = (int*)(ws + off); off += (size_t)NGRP * 4;
    int* wend8  = (int*)(ws + off); off += (size_t)NGRP * 4;
    int* gsize  = (int*)(ws + off); off += (size_t)NBKT2 * 4;
    int* Abase  = (int*)(ws + off); off += (size_t)NBKT2 * 4;
    int* Bbase  = (int*)(ws + off); off += ((size_t)NBKT2 * 4 + 255) / 256 * 256;
    int* hblk   = (int*)(ws + off); off += (size_t)NBLK1 * NBKT2 * 4;
    int* edgesA = (int*)(ws + off); off += (size_t)N_EDGES * 4;
    int* edgesB = (int*)(ws + off); off += (size_t)EPB * 4;
    float* g    = (float*)(ws + off); off += (size_t)N_GRAPHS * DIM * 4;
    int* steal  = (int*)(ws + off); off += 256;

    const int* src = eidx;
    const int* dst = eidx + N_EDGES;

    MegaParams P;
    P.src = src; P.dst = dst; P.batch = batch;
    P.x = (const float4*)x;
    P.Wrel = Wrel; P.brel = brel; P.Wroot = Wroot;
    P.W1 = W1; P.b1 = b1; P.W2 = W2; P.b2 = b2;
    P.y = y;
    P.bf0 = bf0; P.bf1 = bf1;
    P.rpS = rpS; P.wend8 = wend8; P.gsize = gsize; P.Abase = Abase; P.Bbase = Bbase;
    P.hblk = hblk; P.edgesA = edgesA; P.edgesB = edgesB; P.g = g; P.steal = steal;

    // Coop path only if ≥4 blocks/CU achievable AND the launch enqueues cleanly.
    // (R16 lesson: unchecked coop launch failed silently -> zero output.)
    int occ = 0;
    hipError_t oe = hipOccupancyMaxActiveBlocksPerMultiprocessor(&occ, mega_kernel, 256, 0);
    bool coop = (oe == hipSuccess) && (occ >= 4);
    if (coop) {
        void* args[] = { (void*)&P };
        hipError_t le = hipLaunchCooperativeKernel((const void*)mega_kernel,
                                                   dim3(COOP_GRID), dim3(256), args, 0, stream);
        coop = (le == hipSuccess);
    }
    if (!coop) {
        // R15 split pipeline (known-good fallback)
        prep_kernel<<<NBLK1, 256, 0, stream>>>(dst, hblk, (const float4*)x, bf0, bf1, g);
        colscan_kernel<<<NBKT2, 256, 0, stream>>>(hblk, gsize);
        scanb2_kernel<<<1, 256, 0, stream>>>(gsize, Abase, Bbase);
        p1_kernel<<<NBLK1, 256, 0, stream>>>(src, dst, Abase, hblk, edgesA);
        p2_kernel<<<NBKT2, 256, 0, stream>>>(gsize, Abase, Bbase, edgesA, edgesB, rpS, wend8);
        layer_kernel<false><<<NB, 256, 0, stream>>>((const ushort8_t*)bf0, (ushort8_t*)bf1,
            Wrel + 0 * DIM * DIM, brel + 0 * DIM, Wroot + 0 * DIM * DIM,
            rpS, wend8, edgesB, batch, g);
        layer_kernel<false><<<NB, 256, 0, stream>>>((const ushort8_t*)bf1, (ushort8_t*)bf0,
            Wrel + 1 * DIM * DIM, brel + 1 * DIM, Wroot + 1 * DIM * DIM,
            rpS, wend8, edgesB, batch, g);
        layer_kernel<false><<<NB, 256, 0, stream>>>((const ushort8_t*)bf0, (ushort8_t*)bf1,
            Wrel + 2 * DIM * DIM, brel + 2 * DIM, Wroot + 2 * DIM * DIM,
            rpS, wend8, edgesB, batch, g);
        layer_kernel<true><<<NB, 256, 0, stream>>>((const ushort8_t*)bf1, (ushort8_t*)bf0,
            Wrel + 3 * DIM * DIM, brel + 3 * DIM, Wroot + 3 * DIM * DIM,
            rpS, wend8, edgesB, batch, g);
        head_kernel<<<(N_GRAPHS + 255) / 256, 256, 0, stream>>>(g, W1, b1, W2, b2, y);
    }
}

// Round 18
// 369.404 us; speedup vs baseline: 2.2911x; 2.2911x over previous
//
#include <hip/hip_runtime.h>

#define N_NODES 100000
#define N_EDGES 1000000
#define DIM 64
#define N_GRAPHS 1024
#define OUT_DIM 16
#define NLAYERS 4

#define BN 64        // nodes per block in layer kernel
#define NB 1563      // ceil(N_NODES/BN)
#define BLOCK 256    // 4 waves
#define NWAVES 4
#define RPW 16       // rows per wave = 2 padded 8-row groups
#define SA 65        // LDS row stride: 65%32==1 -> 2-way alias, free
#define NGRP 12500   // N_NODES/8 wave-groups

// ---- bucket sort params ----
#define NBKT2 391            // ceil(N_NODES/256) buckets of 256 dst nodes
#define BCH 2048             // edges per pass-1 block
#define NBLK1 489            // ceil(N_EDGES/BCH)
#define SLACK 1800           // per-bucket region slack: 256*7 pad + 8
#define EPB (N_EDGES + NBKT2 * SLACK)
#define SENTSRC N_NODES      // sentinel src -> zero bf16 row

typedef unsigned short ushort8_t __attribute__((ext_vector_type(8)));

__device__ __forceinline__ float b2f(unsigned short u) {
    union { unsigned int i; float f; } c;
    c.i = ((unsigned int)u) << 16;
    return c.f;
}
__device__ __forceinline__ unsigned short f2b(float f) {  // RNE
    union { float f; unsigned int i; } c;
    c.f = f;
    return (unsigned short)((c.i + 0x7FFFu + ((c.i >> 16) & 1u)) >> 16);
}

// block-wide exclusive scan of one int per thread (256 threads); tmp = 4+ ints LDS
__device__ __forceinline__ int blk_excl_scan_256(int v, int tid, int* tmp) {
    int lane = tid & 63, w = tid >> 6;
    int inc = v;
#pragma unroll
    for (int o = 1; o < 64; o <<= 1) { int u = __shfl_up(inc, o, 64); if (lane >= o) inc += u; }
    __syncthreads();              // protect tmp from any previous use
    if (lane == 63) tmp[w] = inc;
    __syncthreads();
    if (tid == 0) { int r = 0; for (int i = 0; i < 4; ++i) { int t2 = tmp[i]; tmp[i] = r; r += t2; } }
    __syncthreads();
    return inc - v + tmp[w];
}

// ---------------- prep: per-block histogram + tobf + zero g + sentinel rows ----------------
__global__ __launch_bounds__(256) void prep_kernel(const int* __restrict__ dst,
                                                   int* __restrict__ hblk,
                                                   const float4* __restrict__ x,
                                                   ushort4* __restrict__ bf0,
                                                   ushort4* __restrict__ bf1,
                                                   float* __restrict__ g) {
    __shared__ int h[NBKT2];
    int tid = threadIdx.x;
    for (int i = tid; i < NBKT2; i += 256) h[i] = 0;
    __syncthreads();
    int e0 = blockIdx.x * BCH;
    int nloc = min(BCH, N_EDGES - e0);
    for (int i = tid; i < nloc; i += 256) atomicAdd(&h[dst[e0 + i] >> 8], 1);  // LDS int: native

    // tobf (independent)
    const int n4 = N_NODES * (DIM / 4);
    for (int i = blockIdx.x * 256 + tid; i < n4; i += NBLK1 * 256) {
        float4 v = x[i];
        ushort4 b;
        b.x = f2b(v.x); b.y = f2b(v.y); b.z = f2b(v.z); b.w = f2b(v.w);
        bf0[i] = b;
    }
    // zero g (independent; pool is fused into last layer)
    const int g4 = N_GRAPHS * (DIM / 4);
    float4 z4 = make_float4(0.f, 0.f, 0.f, 0.f);
    for (int i = blockIdx.x * 256 + tid; i < g4; i += NBLK1 * 256)
        reinterpret_cast<float4*>(g)[i] = z4;
    // zero sentinel rows of both bf buffers
    if (blockIdx.x == 0 && tid < 32) {
        ushort4 z; z.x = 0; z.y = 0; z.z = 0; z.w = 0;
        if (tid < 16) bf0[(size_t)N_NODES * 16 + tid] = z;
        else          bf1[(size_t)N_NODES * 16 + (tid - 16)] = z;
    }
    __syncthreads();
    for (int i = tid; i < NBKT2; i += 256) hblk[(size_t)blockIdx.x * NBKT2 + i] = h[i];
}

// ---- column scan: one block per bucket, scan the 489 per-block counts ----
__global__ __launch_bounds__(256) void colscan_kernel(int* __restrict__ hblk,
                                                      int* __restrict__ gsize) {
    __shared__ int tmp[4];
    int c = blockIdx.x, t = threadIdx.x;
    int i0 = 2 * t, i1 = 2 * t + 1;
    int a = (i0 < NBLK1) ? hblk[(size_t)i0 * NBKT2 + c] : 0;
    int b = (i1 < NBLK1) ? hblk[(size_t)i1 * NBKT2 + c] : 0;
    int s = blk_excl_scan_256(a + b, t, tmp);
    if (i0 < NBLK1) hblk[(size_t)i0 * NBKT2 + c] = s;
    if (i1 < NBLK1) hblk[(size_t)i1 * NBKT2 + c] = s + a;
    if (t == 255) gsize[c] = s + a + b;   // column total
}

// tiny single block: scan 391 bucket totals -> Abase, Bbase
__global__ __launch_bounds__(256) void scanb2_kernel(const int* __restrict__ gsize,
                                                     int* __restrict__ Abase,
                                                     int* __restrict__ Bbase) {
    __shared__ int tmp[4];
    int t = threadIdx.x;
    int c0 = 2 * t, c1 = 2 * t + 1;
    int a = (c0 < NBKT2) ? gsize[c0] : 0;
    int b = (c1 < NBKT2) ? gsize[c1] : 0;
    int s = blk_excl_scan_256(a + b, t, tmp);
    if (c0 < NBKT2) Abase[c0] = s;
    if (c1 < NBKT2) Abase[c1] = s + a;
    int a2 = (c0 < NBKT2) ? a + SLACK : 0;
    int b2 = (c1 < NBKT2) ? b + SLACK : 0;
    int s2 = blk_excl_scan_256(a2 + b2, t, tmp);
    if (c0 < NBKT2) Bbase[c0] = s2;
    if (c1 < NBKT2) Bbase[c1] = s2 + a2;
}

__global__ __launch_bounds__(256) void p1_kernel(const int* __restrict__ src,
                                                 const int* __restrict__ dst,
                                                 const int* __restrict__ Abase,
                                                 const int* __restrict__ hblk,
                                                 int* __restrict__ edgesA) {
    __shared__ int h[NBKT2], start[NBKT2], curb[NBKT2], resv[NBKT2], tmp[4];
    __shared__ int sortedv[BCH];
    __shared__ unsigned short sortedb[BCH];
    int tid = threadIdx.x;
    int e0 = blockIdx.x * BCH;
    int nloc = min(BCH, N_EDGES - e0);
    for (int i = tid; i < NBKT2; i += 256) h[i] = 0;
    __syncthreads();
    int myc[8], myv[8];
#pragma unroll
    for (int k = 0; k < 8; ++k) {
        int i = k * 256 + tid;
        if (i < nloc) {
            int e = e0 + i;
            int d = dst[e];
            myc[k] = d >> 8;
            myv[k] = ((d & 255) << 17) | src[e];   // 8b local dst | 17b src
            atomicAdd(&h[myc[k]], 1);
        } else myc[k] = -1;
    }
    __syncthreads();
    {   // scan h -> start (2 elems/thread over 512 slots)
        int a = (2 * tid < NBKT2) ? h[2 * tid] : 0;
        int b = (2 * tid + 1 < NBKT2) ? h[2 * tid + 1] : 0;
        int s = blk_excl_scan_256(a + b, tid, tmp);
        if (2 * tid < NBKT2) start[2 * tid] = s;
        if (2 * tid + 1 < NBKT2) start[2 * tid + 1] = s + a;
    }
    __syncthreads();
    for (int i = tid; i < NBKT2; i += 256) curb[i] = start[i];
    __syncthreads();
#pragma unroll
    for (int k = 0; k < 8; ++k) if (myc[k] >= 0) {
        int r = atomicAdd(&curb[myc[k]], 1);
        sortedv[r] = myv[k];
        sortedb[r] = (unsigned short)myc[k];
    }
    __syncthreads();
    // reservation = precomputed block-prefix (colscan) -- no global atomics
    for (int i = tid; i < NBKT2; i += 256) resv[i] = hblk[(size_t)blockIdx.x * NBKT2 + i];
    __syncthreads();
    for (int i = tid; i < nloc; i += 256) {                  // coalesced run writes
        int c = sortedb[i];
        edgesA[Abase[c] + resv[c] + (i - start[c])] = sortedv[i];
    }
}

// one block per bucket: count -> 8-padded scan -> private-region scatter + pads,
// emits per-8-node-group [start,end) directly (rpS / wend8)
__global__ __launch_bounds__(256) void p2_kernel(const int* __restrict__ gsize,
                                                 const int* __restrict__ Abase,
                                                 const int* __restrict__ Bbase,
                                                 const int* __restrict__ edgesA,
                                                 int* __restrict__ edgesB,
                                                 int* __restrict__ rpS,
                                                 int* __restrict__ wend8) {
    __shared__ int cnt[256], off[256], pend[256], curx[256], tmp[4];
    int b = blockIdx.x, tid = threadIdx.x;
    int nb0 = b * 256;
    int nn = min(256, N_NODES - nb0);
    int ne = gsize[b];
    int abase = Abase[b], bbase = Bbase[b];
    cnt[tid] = 0;
    __syncthreads();
    for (int i = tid; i < ne; i += 256) atomicAdd(&cnt[edgesA[abase + i] >> 17], 1);
    __syncthreads();
    int c = cnt[tid];
    int c8 = (tid < nn) ? ((c + 7) & ~7) : 0;
    int o = blk_excl_scan_256(c8, tid, tmp);
    off[tid] = o; pend[tid] = o + c8; curx[tid] = bbase + o;
    __syncthreads();
    int gc = nn >> 3;
    if (tid < gc) {
        rpS[(nb0 >> 3) + tid] = bbase + off[tid * 8];
        wend8[(nb0 >> 3) + tid] = bbase + pend[tid * 8 + 7];
    }
    for (int i = tid; i < ne; i += 256) {
        int p = edgesA[abase + i];
        int dl = p >> 17;
        int pos = atomicAdd(&curx[dl], 1);
        edgesB[pos] = ((dl & 7) << 17) | (p & 0x1FFFF);   // wave-local row | src
    }
    __syncthreads();
    if (tid < nn) {   // sentinel pads
        int pe = bbase + pend[tid];
        int sent = ((tid & 7) << 17) | SENTSRC;
        for (int pos = curx[tid]; pos < pe; ++pos) edgesB[pos] = sent;
    }
}

__device__ __forceinline__ void flush_row(float* a, int row, int lane, float* agg_s) {
#pragma unroll
    for (int j = 0; j < 8; ++j) {
        a[j] += __shfl_xor(a[j], 8, 64);
        a[j] += __shfl_xor(a[j], 16, 64);
        a[j] += __shfl_xor(a[j], 32, 64);
    }
    if ((lane >> 3) == 0) {
#pragma unroll
        for (int j = 0; j < 8; ++j)
            agg_s[row * SA + (lane & 7) * 8 + j] = a[j];
    }
}

// ---------------- fused GraphConv layer: bf16-only h (fp32 compute) ----------
// R15 verbatim: the R17 refactor (shared __device__ body) inflated VGPR 40->108
// and cost 3x via occupancy collapse. Keep this as a monolithic template kernel.
template <bool LAST>
__global__ __launch_bounds__(BLOCK) void layer_kernel(
    const ushort8_t* __restrict__ hbf_in, ushort8_t* __restrict__ hbf_out,
    const float* __restrict__ Wrel, const float* __restrict__ brel,
    const float* __restrict__ Wroot,
    const int* __restrict__ rpS, const int* __restrict__ wend8,
    const int* __restrict__ edges8,
    const int* __restrict__ batch, float* __restrict__ g) {
    __shared__ float agg_s[BN * SA];   // 16.6 KB
    const int tid = threadIdx.x;
    const int lane = tid & 63;
    const int wave = __builtin_amdgcn_readfirstlane(tid >> 6);
    const int grp8 = lane >> 3;
    const int gl8 = lane & 7;
    const int node0 = blockIdx.x * BN;
    const int nvalid = min(BN, N_NODES - node0);

#pragma unroll
    for (int r = 0; r < RPW; ++r) agg_s[(wave * RPW + r) * SA + lane] = 0.f;

    // Phase A: two 8-row segments per wave
#pragma unroll
    for (int seg = 0; seg < 2; ++seg) {
        const int gg = blockIdx.x * 8 + wave * 2 + seg;
        if (gg >= NGRP) break;
        const int eb = rpS[gg];
        const int nst = (wend8[gg] - eb) >> 3;
        if (nst <= 0) continue;
        const int rbase = wave * RPW + seg * 8;

        float a[8];
#pragma unroll
        for (int j = 0; j < 8; ++j) a[j] = 0.f;
        int cur = -1;

        const int lmax = nst * 8 - 1;
        const int l32 = lane & 31;
        int pv0 = edges8[eb + min(l32, lmax)];
        int pv1 = edges8[eb + min(32 + l32, lmax)];
        ushort8_t U0[4];
#pragma unroll
        for (int i = 0; i < 4; ++i) {
            int ps = __shfl(pv0, i * 8 + grp8, 64);
            U0[i] = hbf_in[(size_t)(ps & 0x1FFFF) * 8 + gl8];
        }
        for (int c = 0; c * 4 < nst; ++c) {
            int pvn = edges8[eb + min((c + 2) * 32 + l32, lmax)];
            ushort8_t Un[4];
#pragma unroll
            for (int i = 0; i < 4; ++i) {
                int ps = __shfl(pv1, i * 8 + grp8, 64);
                Un[i] = hbf_in[(size_t)(ps & 0x1FFFF) * 8 + gl8];
            }
#pragma unroll
            for (int i = 0; i < 4; ++i) {
                int t = c * 4 + i;
                if (t < nst) {
                    int lr = __builtin_amdgcn_readfirstlane(__shfl(pv0, i * 8, 64)) >> 17;
                    if (lr != cur) {
                        if (cur >= 0) flush_row(a, rbase + cur, lane, agg_s);
                        cur = lr;
#pragma unroll
                        for (int j = 0; j < 8; ++j) a[j] = 0.f;
                    }
#pragma unroll
                    for (int j = 0; j < 8; ++j) a[j] += b2f(U0[i][j]);
                }
            }
            pv0 = pv1; pv1 = pvn;
#pragma unroll
            for (int i = 0; i < 4; ++i) U0[i] = Un[i];
        }
        if (cur >= 0) flush_row(a, rbase + cur, lane, agg_s);
    }
    __syncthreads();

    // Phase B: node = lane, dims [wave*16, +16); own row read from bf16
    const int d0 = wave * 16;
    float out[16];
#pragma unroll
    for (int j = 0; j < 16; ++j) out[j] = brel[d0 + j];
    const float* ar = &agg_s[lane * SA];
    const int nrow = min(node0 + lane, N_NODES - 1);
    const ushort8_t* xrow8 = &hbf_in[(size_t)nrow * 8];
    for (int kk = 0; kk < 8; ++kk) {
        ushort8_t xq = xrow8[kk];   // own row: 8KB/block, L2/L1-warm
#pragma unroll
        for (int c = 0; c < 8; ++c) {
            int k = kk * 8 + c;
            float av = ar[k];
            float xv = b2f(xq[c]);
            const float* wr = &Wrel[k * DIM + d0];
            const float* wo = &Wroot[k * DIM + d0];
#pragma unroll
            for (int j = 0; j < 16; ++j)
                out[j] = fmaf(av, wr[j], fmaf(xv, wo[j], out[j]));
        }
    }

    __syncthreads();
#pragma unroll
    for (int j = 0; j < 16; ++j) agg_s[lane * SA + d0 + j] = fmaxf(out[j], 0.f);
    __syncthreads();

    if (LAST) {
        // fused global_add_pool: wave 0, lane = dim; batch is sorted
        if (wave == 0) {
            float acc = 0.f;
            int cur = batch[node0];
            for (int nl = 0; nl < nvalid; ++nl) {
                int bv = batch[node0 + nl];          // wave-uniform scalar
                float v = agg_s[nl * SA + lane];
                if (bv != cur) {
                    unsafeAtomicAdd(&g[(size_t)cur * DIM + lane], acc);
                    acc = 0.f; cur = bv;
                }
                acc += v;
            }
            unsafeAtomicAdd(&g[(size_t)cur * DIM + lane], acc);
        }
    } else {
        // coalesced bf16 store only (transpose via agg_s)
        for (int i = tid; i < nvalid * 8; i += BLOCK) {
            int nl = i >> 3, c8 = i & 7;
            const float* xp = &agg_s[nl * SA + c8 * 8];
            ushort8_t b;
#pragma unroll
            for (int j = 0; j < 8; ++j) b[j] = f2b(xp[j]);
            hbf_out[(size_t)(node0 + nl) * 8 + c8] = b;
        }
    }
}

// ---------------- classifier head ----------------
__global__ __launch_bounds__(256) void head_kernel(
    const float* __restrict__ g, const float* __restrict__ W1, const float* __restrict__ b1,
    const float* __restrict__ W2, const float* __restrict__ b2, float* __restrict__ y) {
    int gid = blockIdx.x * blockDim.x + threadIdx.x;
    if (gid >= N_GRAPHS) return;
    float t[DIM];
#pragma unroll
    for (int d = 0; d < DIM; ++d) t[d] = b1[d];
    const float4* gp = reinterpret_cast<const float4*>(g + (size_t)gid * DIM);
    for (int kk = 0; kk < DIM / 4; ++kk) {
        float4 gv = gp[kk];
        float ga[4] = {gv.x, gv.y, gv.z, gv.w};
#pragma unroll
        for (int c = 0; c < 4; ++c) {
            int k = 4 * kk + c;
            float v = ga[c];
#pragma unroll
            for (int d = 0; d < DIM; ++d) t[d] = fmaf(v, W1[k * DIM + d], t[d]);
        }
    }
#pragma unroll
    for (int d = 0; d < DIM; ++d) t[d] = fmaxf(t[d], 0.f);
    for (int o = 0; o < OUT_DIM; ++o) {
        float acc = b2[o];
#pragma unroll
        for (int d = 0; d < DIM; ++d) acc = fmaf(t[d], W2[d * OUT_DIM + o], acc);
        y[(size_t)gid * OUT_DIM + o] = acc;
    }
}

extern "C" void kernel_launch(void* const* d_in, const int* in_sizes, int n_in,
                              void* d_out, int out_size, void* d_ws, size_t ws_size,
                              hipStream_t stream) {
    const float* x     = (const float*)d_in[0];
    const int*   eidx  = (const int*)d_in[1];
    const int*   batch = (const int*)d_in[2];
    const float* Wrel  = (const float*)d_in[3];
    const float* brel  = (const float*)d_in[4];
    const float* Wroot = (const float*)d_in[5];
    const float* W1    = (const float*)d_in[6];
    const float* b1    = (const float*)d_in[7];
    const float* W2    = (const float*)d_in[8];
    const float* b2    = (const float*)d_in[9];
    float* y = (float*)d_out;

    char* ws = (char*)d_ws;
    const size_t BFBYTES = (size_t)(N_NODES + 1) * DIM * sizeof(unsigned short); // 12.8 MB + zero row
    size_t off = 0;
    ushort4* bf0 = (ushort4*)(ws + off); off += (BFBYTES + 255) / 256 * 256;
    ushort4* bf1 = (ushort4*)(ws + off); off += (BFBYTES + 255) / 256 * 256;
    int* rpS    = (int*)(ws + off); off += (size_t)NGRP * 4;
    int* wend8  = (int*)(ws + off); off += (size_t)NGRP * 4;
    int* gsize  = (int*)(ws + off); off += (size_t)NBKT2 * 4;
    int* Abase  = (int*)(ws + off); off += (size_t)NBKT2 * 4;
    int* Bbase  = (int*)(ws + off); off += ((size_t)NBKT2 * 4 + 255) / 256 * 256;
    int* hblk   = (int*)(ws + off); off += (size_t)NBLK1 * NBKT2 * 4;  // 765 KB
    int* edgesA = (int*)(ws + off); off += (size_t)N_EDGES * 4;
    int* edgesB = (int*)(ws + off); off += (size_t)EPB * 4;
    float* g    = (float*)(ws + off); off += (size_t)N_GRAPHS * DIM * 4;

    const int* src = eidx;
    const int* dst = eidx + N_EDGES;

    // CSR build: prep -> parallel column scan -> tiny total scan -> p1 -> p2
    prep_kernel<<<NBLK1, 256, 0, stream>>>(dst, hblk, (const float4*)x, bf0, bf1, g);
    colscan_kernel<<<NBKT2, 256, 0, stream>>>(hblk, gsize);
    scanb2_kernel<<<1, 256, 0, stream>>>(gsize, Abase, Bbase);
    p1_kernel<<<NBLK1, 256, 0, stream>>>(src, dst, Abase, hblk, edgesA);
    p2_kernel<<<NBKT2, 256, 0, stream>>>(gsize, Abase, Bbase, edgesA, edgesB, rpS, wend8);

    // 4 GraphConv layers, bf16 ping-pong; last fuses pool
    layer_kernel<false><<<NB, BLOCK, 0, stream>>>((const ushort8_t*)bf0, (ushort8_t*)bf1,
        Wrel + 0 * DIM * DIM, brel + 0 * DIM, Wroot + 0 * DIM * DIM,
        rpS, wend8, edgesB, batch, g);
    layer_kernel<false><<<NB, BLOCK, 0, stream>>>((const ushort8_t*)bf1, (ushort8_t*)bf0,
        Wrel + 1 * DIM * DIM, brel + 1 * DIM, Wroot + 1 * DIM * DIM,
        rpS, wend8, edgesB, batch, g);
    layer_kernel<false><<<NB, BLOCK, 0, stream>>>((const ushort8_t*)bf0, (ushort8_t*)bf1,
        Wrel + 2 * DIM * DIM, brel + 2 * DIM, Wroot + 2 * DIM * DIM,
        rpS, wend8, edgesB, batch, g);
    layer_kernel<true><<<NB, BLOCK, 0, stream>>>((const ushort8_t*)bf1, (ushort8_t*)bf0,
        Wrel + 3 * DIM * DIM, brel + 3 * DIM, Wroot + 3 * DIM * DIM,
        rpS, wend8, edgesB, batch, g);

    // head
    head_kernel<<<(N_GRAPHS + 255) / 256, 256, 0, stream>>>(g, W1, b1, W2, b2, y);
}